// Round 4
// baseline (325.613 us; speedup 1.0000x reference)
//
#include <hip/hip_runtime.h>

#define N_NODES 50000
#define N_EDGES 800000
#define N_FEAT  128
#define N_HID   64

#define B_LOG   6
#define BSZ     64                      // dst values per bucket
#define NBK     ((N_NODES + BSZ - 1) / BSZ)   // 782
#define SLOT    1408                    // E[1024] + 12 sigma

__device__ inline void fma4(float4& acc, float s, const float4& w) {
    acc.x = fmaf(s, w.x, acc.x);
    acc.y = fmaf(s, w.y, acc.y);
    acc.z = fmaf(s, w.z, acc.z);
    acc.w = fmaf(s, w.w, acc.w);
}

// ---------- tiled GEMM: o[row][col] = sum_k a[row*K+k] * w[k*64+col] ----------
template <int K>
__global__ __launch_bounds__(256) void gemm_tile(const float* __restrict__ a,
                                                 const float* __restrict__ w,
                                                 float* __restrict__ o) {
    __shared__ float lw[K * N_HID];
    int tid = threadIdx.x;
    for (int idx = tid * 4; idx < K * N_HID; idx += 256 * 4)
        *(float4*)&lw[idx] = *(const float4*)&w[idx];
    __syncthreads();

    int row0 = blockIdx.x * 32 + (tid >> 4) * 2;
    if (row0 >= N_NODES) return;
    bool two = (row0 + 1) < N_NODES;
    int c4 = (tid & 15) * 4;

    const float* a0 = a + (long)row0 * K;
    const float* a1 = two ? (a0 + K) : a0;

    float4 acc0 = make_float4(0.f, 0.f, 0.f, 0.f);
    float4 acc1 = acc0;

#pragma unroll 8
    for (int k4 = 0; k4 < K / 4; ++k4) {
        float4 xa = *(const float4*)(a0 + k4 * 4);
        float4 xb = *(const float4*)(a1 + k4 * 4);
        const float* wk = &lw[(k4 * 4) * N_HID + c4];
        float4 w0 = *(const float4*)(wk);
        float4 w1 = *(const float4*)(wk + N_HID);
        float4 w2 = *(const float4*)(wk + 2 * N_HID);
        float4 w3 = *(const float4*)(wk + 3 * N_HID);
        fma4(acc0, xa.x, w0); fma4(acc1, xb.x, w0);
        fma4(acc0, xa.y, w1); fma4(acc1, xb.y, w1);
        fma4(acc0, xa.z, w2); fma4(acc1, xb.z, w2);
        fma4(acc0, xa.w, w3); fma4(acc1, xb.w, w3);
    }

    float* op = o + (long)row0 * N_HID + c4;
    *(float4*)op = acc0;
    if (two) *(float4*)(op + N_HID) = acc1;
}

// ---------- CSR build: two-level bucket sort ----------
// phase 1: scatter edges into per-bucket slabs (bucket = dst>>6)
__global__ void scatter_bucket(const int* __restrict__ src, const int* __restrict__ dst,
                               const float* __restrict__ ew, int* __restrict__ bcnt,
                               uint2* __restrict__ slab8, unsigned char* __restrict__ slabd) {
    int e = blockIdx.x * blockDim.x + threadIdx.x;
    if (e >= N_EDGES) return;
    int d = dst[e];
    int b = d >> B_LOG;
    int p = atomicAdd(&bcnt[b], 1);
    if (p < SLOT) {
        slab8[(long)b * SLOT + p] = make_uint2((unsigned)src[e], __float_as_uint(ew[e]));
        slabd[(long)b * SLOT + p] = (unsigned char)(d & (BSZ - 1));
    }
}

// phase 2: single-block exclusive scan of bucket counts
__global__ void bscan(const int* __restrict__ bcnt, int* __restrict__ bstart) {
    __shared__ int lds[1024];
    int t = threadIdx.x;
    int v = (t < NBK) ? min(bcnt[t], SLOT) : 0;
    lds[t] = v;
    __syncthreads();
    for (int off = 1; off < 1024; off <<= 1) {
        int u = (t >= off) ? lds[t - off] : 0;
        __syncthreads();
        lds[t] += u;
        __syncthreads();
    }
    if (t < NBK) bstart[t] = lds[t] - v;
    if (t == NBK - 1) bstart[NBK] = lds[t];
}

// phase 3: per-bucket LDS counting sort -> final edges + start[]
__global__ __launch_bounds__(256) void sort_bucket(const uint2* __restrict__ slab8,
                                                   const unsigned char* __restrict__ slabd,
                                                   const int* __restrict__ bcnt,
                                                   const int* __restrict__ bstart,
                                                   int2* __restrict__ edges,
                                                   int* __restrict__ start) {
    __shared__ int cnt[BSZ];
    __shared__ int cur[BSZ];
    int b = blockIdx.x;
    int t = threadIdx.x;
    int c = min(bcnt[b], SLOT);
    int base = bstart[b];
    const long sb = (long)b * SLOT;

    if (t < BSZ) cnt[t] = 0;
    __syncthreads();
    for (int i = t; i < c; i += 256)
        atomicAdd(&cnt[slabd[sb + i]], 1);
    __syncthreads();
    if (t == 0) {
        int s = 0;
        for (int i = 0; i < BSZ; ++i) { int v = cnt[i]; cnt[i] = s; cur[i] = s; s += v; }
    }
    __syncthreads();
    int node0 = b << B_LOG;
    if (t < BSZ && node0 + t < N_NODES)
        start[node0 + t] = base + cnt[t];
    if (b == 0 && t == 0) start[N_NODES] = N_EDGES;
    for (int i = t; i < c; i += 256) {
        uint2 r = slab8[sb + i];
        int dl = slabd[sb + i];
        int p = atomicAdd(&cur[dl], 1);
        edges[base + p] = make_int2((int)r.x, (int)r.y);
    }
}

// ---------- pull aggregation, unroll-4 for latency overlap ----------
template <bool RELU>
__global__ void gcn_agg(const float* __restrict__ hw, const int2* __restrict__ edges,
                        const int* __restrict__ start, const float* __restrict__ b,
                        float* __restrict__ o) {
    int t = blockIdx.x * blockDim.x + threadIdx.x;
    int n = t >> 6;
    int f = t & 63;
    if (n >= N_NODES) return;
    int i0 = start[n], i1 = start[n + 1];
    float bias = b[f];
    float acc = 0.f;
    int i = i0;
    for (; i + 4 <= i1; i += 4) {
        int2 e0 = edges[i];
        int2 e1 = edges[i + 1];
        int2 e2 = edges[i + 2];
        int2 e3 = edges[i + 3];
        float v0 = hw[(long)e0.x * N_HID + f];
        float v1 = hw[(long)e1.x * N_HID + f];
        float v2 = hw[(long)e2.x * N_HID + f];
        float v3 = hw[(long)e3.x * N_HID + f];
        acc = fmaf(v0, __int_as_float(e0.y), acc);
        acc = fmaf(v1, __int_as_float(e1.y), acc);
        acc = fmaf(v2, __int_as_float(e2.y), acc);
        acc = fmaf(v3, __int_as_float(e3.y), acc);
    }
    for (; i < i1; ++i) {
        int2 ed = edges[i];
        acc = fmaf(hw[(long)ed.x * N_HID + f], __int_as_float(ed.y), acc);
    }
    acc += bias;
    if (RELU) acc = fmaxf(acc, 0.f);
    o[(long)n * N_HID + f] = acc;
}

extern "C" void kernel_launch(void* const* d_in, const int* in_sizes, int n_in,
                              void* d_out, int out_size, void* d_ws, size_t ws_size,
                              hipStream_t stream) {
    const float* x  = (const float*)d_in[0];
    const int*   ei = (const int*)d_in[1];   // [2, E] flat: src then dst
    const float* ew = (const float*)d_in[2];
    const float* w1 = (const float*)d_in[3];
    const float* b1 = (const float*)d_in[4];
    const float* w2 = (const float*)d_in[5];
    const float* b2 = (const float*)d_in[6];
    float* out = (float*)d_out;

    const int* src = ei;
    const int* dst = ei + N_EDGES;

    // workspace: regionA time-shared between slab (CSR build) and hw (layers)
    char* ws = (char*)d_ws;
    const size_t REGA = (size_t)N_NODES * N_HID * sizeof(float);      // 12.8 MB
    float* hw    = (float*)ws;
    uint2* slab8 = (uint2*)ws;                                        // 8.81 MB
    unsigned char* slabd = (unsigned char*)(ws + (size_t)NBK * SLOT * sizeof(uint2)); // 1.10 MB
    int2* edges  = (int2*)(ws + REGA);                                // 6.4 MB
    int*  start  = (int*)(edges + N_EDGES);                           // 50001
    int*  bcnt   = start + N_NODES + 8;                               // 782
    int*  bstart = bcnt + NBK;                                        // 783

    dim3 blk(256);
    dim3 egrid((N_EDGES + 255) / 256);
    dim3 ngrid((N_NODES * N_HID + 255) / 256);
    dim3 ggrid((N_NODES + 31) / 32);

    // ---- build CSR (bucketed counting sort) ----
    hipMemsetAsync(bcnt, 0, (size_t)NBK * sizeof(int), stream);
    scatter_bucket<<<egrid, blk, 0, stream>>>(src, dst, ew, bcnt, slab8, slabd);
    bscan<<<1, 1024, 0, stream>>>(bcnt, bstart);
    sort_bucket<<<NBK, blk, 0, stream>>>(slab8, slabd, bcnt, bstart, edges, start);

    // ---- layer 1: hw = x@w1 (overwrites slab); h = relu(agg+b1) -> d_out ----
    gemm_tile<N_FEAT><<<ggrid, blk, 0, stream>>>(x, w1, hw);
    gcn_agg<true><<<ngrid, blk, 0, stream>>>(hw, edges, start, b1, out);

    // ---- layer 2: hw = h@w2; out = agg + b2 ----
    gemm_tile<N_HID><<<ggrid, blk, 0, stream>>>(out, w2, hw);
    gcn_agg<false><<<ngrid, blk, 0, stream>>>(hw, edges, start, b2, out);
}

// Round 5
// 156.718 us; speedup vs baseline: 2.0777x; 2.0777x over previous
//
#include <hip/hip_runtime.h>

#define N_NODES 50000
#define N_EDGES 800000
#define N_FEAT  128
#define N_HID   64

#define BKT_LOG 9
#define BKT_SZ  512                                  // nodes per bucket
#define NBKT    ((N_NODES + BKT_SZ - 1) / BKT_SZ)    // 98
#define CH      4096                                 // edges per partition block
#define NB1     ((N_EDGES + CH - 1) / CH)            // 196

__device__ inline void fma4(float4& acc, float s, const float4& w) {
    acc.x = fmaf(s, w.x, acc.x);
    acc.y = fmaf(s, w.y, acc.y);
    acc.z = fmaf(s, w.z, acc.z);
    acc.w = fmaf(s, w.w, acc.w);
}

// ---------- tiled GEMM: o[row][col] = sum_k a[row*K+k] * w[k*64+col] ----------
template <int K>
__global__ __launch_bounds__(256) void gemm_tile(const float* __restrict__ a,
                                                 const float* __restrict__ w,
                                                 float* __restrict__ o) {
    __shared__ float lw[K * N_HID];
    int tid = threadIdx.x;
    for (int idx = tid * 4; idx < K * N_HID; idx += 256 * 4)
        *(float4*)&lw[idx] = *(const float4*)&w[idx];
    __syncthreads();

    int row0 = blockIdx.x * 32 + (tid >> 4) * 2;
    if (row0 >= N_NODES) return;
    bool two = (row0 + 1) < N_NODES;
    int c4 = (tid & 15) * 4;

    const float* a0 = a + (long)row0 * K;
    const float* a1 = two ? (a0 + K) : a0;

    float4 acc0 = make_float4(0.f, 0.f, 0.f, 0.f);
    float4 acc1 = acc0;

#pragma unroll 8
    for (int k4 = 0; k4 < K / 4; ++k4) {
        float4 xa = *(const float4*)(a0 + k4 * 4);
        float4 xb = *(const float4*)(a1 + k4 * 4);
        const float* wk = &lw[(k4 * 4) * N_HID + c4];
        float4 w0 = *(const float4*)(wk);
        float4 w1 = *(const float4*)(wk + N_HID);
        float4 w2 = *(const float4*)(wk + 2 * N_HID);
        float4 w3 = *(const float4*)(wk + 3 * N_HID);
        fma4(acc0, xa.x, w0); fma4(acc1, xb.x, w0);
        fma4(acc0, xa.y, w1); fma4(acc1, xb.y, w1);
        fma4(acc0, xa.z, w2); fma4(acc1, xb.z, w2);
        fma4(acc0, xa.w, w3); fma4(acc1, xb.w, w3);
    }

    float* op = o + (long)row0 * N_HID + c4;
    *(float4*)op = acc0;
    if (two) *(float4*)(op + N_HID) = acc1;
}

// ---------- CSR build: decoupled radix partition (NO global atomics) ----------
// phase 1: per-block LDS histogram of bucket = dst>>9
__global__ __launch_bounds__(256) void binhist(const int* __restrict__ dst,
                                               int* __restrict__ cnt) {
    __shared__ int h[NBKT];
    int t = threadIdx.x;
    if (t < NBKT) h[t] = 0;
    __syncthreads();
    int e0 = blockIdx.x * CH;
    for (int i = t; i < CH; i += 256) {
        int e = e0 + i;
        if (e < N_EDGES) atomicAdd(&h[dst[e] >> BKT_LOG], 1);
    }
    __syncthreads();
    if (t < NBKT) cnt[blockIdx.x * NBKT + t] = h[t];
}

// phase 2: single block computes bucket bases + per-(block,bucket) offsets
__global__ __launch_bounds__(128) void binscan(const int* __restrict__ cnt,
                                               int* __restrict__ off,
                                               int* __restrict__ bstart) {
    __shared__ int tot[NBKT];
    int t = threadIdx.x;
    if (t < NBKT) {
        int s = 0;
        for (int b = 0; b < NB1; ++b) s += cnt[b * NBKT + t];
        tot[t] = s;
    }
    __syncthreads();
    if (t == 0) {
        int s = 0;
        for (int i = 0; i < NBKT; ++i) { bstart[i] = s; s += tot[i]; }
        bstart[NBKT] = s;   // == N_EDGES
    }
    __syncthreads();
    if (t < NBKT) {
        int run = bstart[t];
        for (int b = 0; b < NB1; ++b) {
            off[b * NBKT + t] = run;
            run += cnt[b * NBKT + t];
        }
    }
}

// phase 3: place edges into bucket-partitioned slab via LDS cursors
__global__ __launch_bounds__(256) void binscatter(const int* __restrict__ src,
                                                  const int* __restrict__ dst,
                                                  const float* __restrict__ ew,
                                                  const int* __restrict__ off,
                                                  uint2* __restrict__ slab) {
    __shared__ int cur[NBKT];
    int t = threadIdx.x;
    if (t < NBKT) cur[t] = off[blockIdx.x * NBKT + t];
    __syncthreads();
    int e0 = blockIdx.x * CH;
    for (int i = t; i < CH; i += 256) {
        int e = e0 + i;
        if (e >= N_EDGES) continue;
        int d = dst[e];
        int bin = d >> BKT_LOG;
        int p = atomicAdd(&cur[bin], 1);
        slab[p] = make_uint2((unsigned)src[e] | ((unsigned)(d & (BKT_SZ - 1)) << 16),
                             __float_as_uint(ew[e]));
    }
}

// phase 4: per-bucket LDS counting sort -> final edges + start[]
__global__ __launch_bounds__(512) void sort_bucket(const uint2* __restrict__ slab,
                                                   const int* __restrict__ bstart,
                                                   int2* __restrict__ edges,
                                                   int* __restrict__ start) {
    __shared__ int h[BKT_SZ];
    __shared__ int sc[BKT_SZ];
    int b = blockIdx.x;
    int t = threadIdx.x;
    int base = bstart[b];
    int c = bstart[b + 1] - base;

    h[t] = 0;
    __syncthreads();
    for (int i = t; i < c; i += 512)
        atomicAdd(&h[(slab[base + i].x >> 16) & (BKT_SZ - 1)], 1);
    __syncthreads();
    int v = h[t];
    sc[t] = v;
    __syncthreads();
    for (int o = 1; o < BKT_SZ; o <<= 1) {
        int u = (t >= o) ? sc[t - o] : 0;
        __syncthreads();
        sc[t] += u;
        __syncthreads();
    }
    int excl = sc[t] - v;                 // exclusive prefix within bucket
    int g = (b << BKT_LOG) + t;
    if (g < N_NODES) start[g] = base + excl;
    if (b == NBKT - 1 && t == 0) start[N_NODES] = N_EDGES;
    h[t] = base + excl;                   // reuse as cursor
    __syncthreads();
    for (int i = t; i < c; i += 512) {
        uint2 r = slab[base + i];
        int p = atomicAdd(&h[(r.x >> 16) & (BKT_SZ - 1)], 1);
        edges[p] = make_int2((int)(r.x & 0xFFFF), (int)r.y);
    }
}

// ---------- pull aggregation, unroll-4 for latency overlap ----------
template <bool RELU>
__global__ void gcn_agg(const float* __restrict__ hw, const int2* __restrict__ edges,
                        const int* __restrict__ start, const float* __restrict__ b,
                        float* __restrict__ o) {
    int t = blockIdx.x * blockDim.x + threadIdx.x;
    int n = t >> 6;
    int f = t & 63;
    if (n >= N_NODES) return;
    int i0 = start[n], i1 = start[n + 1];
    float bias = b[f];
    float acc = 0.f;
    int i = i0;
    for (; i + 4 <= i1; i += 4) {
        int2 e0 = edges[i];
        int2 e1 = edges[i + 1];
        int2 e2 = edges[i + 2];
        int2 e3 = edges[i + 3];
        float v0 = hw[(long)e0.x * N_HID + f];
        float v1 = hw[(long)e1.x * N_HID + f];
        float v2 = hw[(long)e2.x * N_HID + f];
        float v3 = hw[(long)e3.x * N_HID + f];
        acc = fmaf(v0, __int_as_float(e0.y), acc);
        acc = fmaf(v1, __int_as_float(e1.y), acc);
        acc = fmaf(v2, __int_as_float(e2.y), acc);
        acc = fmaf(v3, __int_as_float(e3.y), acc);
    }
    for (; i < i1; ++i) {
        int2 ed = edges[i];
        acc = fmaf(hw[(long)ed.x * N_HID + f], __int_as_float(ed.y), acc);
    }
    acc += bias;
    if (RELU) acc = fmaxf(acc, 0.f);
    o[(long)n * N_HID + f] = acc;
}

extern "C" void kernel_launch(void* const* d_in, const int* in_sizes, int n_in,
                              void* d_out, int out_size, void* d_ws, size_t ws_size,
                              hipStream_t stream) {
    const float* x  = (const float*)d_in[0];
    const int*   ei = (const int*)d_in[1];   // [2, E] flat: src then dst
    const float* ew = (const float*)d_in[2];
    const float* w1 = (const float*)d_in[3];
    const float* b1 = (const float*)d_in[4];
    const float* w2 = (const float*)d_in[5];
    const float* b2 = (const float*)d_in[6];
    float* out = (float*)d_out;

    const int* src = ei;
    const int* dst = ei + N_EDGES;

    // workspace layout; region A (hw, 12.8 MB) time-shares slab+cnt+off,
    // which are all dead before gemm_tile first writes hw.
    char* ws = (char*)d_ws;
    const size_t SLAB_B = (size_t)N_EDGES * sizeof(uint2);            // 6.4 MB
    const size_t REGA   = (size_t)N_NODES * N_HID * sizeof(float);    // 12.8 MB
    float* hw    = (float*)ws;
    uint2* slab  = (uint2*)ws;                                        // [0, 6.4 MB)
    int*   cnt   = (int*)(ws + SLAB_B);                               // 196*98 ints
    int*   off   = cnt + NB1 * NBKT;                                  // 196*98 ints
    int2*  edges = (int2*)(ws + REGA);                                // 6.4 MB
    int*   start = (int*)(ws + REGA + SLAB_B);                        // 50001 ints
    int*   bstart = start + N_NODES + 3;                              // 99 ints

    dim3 blk(256);
    dim3 ngrid((N_NODES * N_HID + 255) / 256);   // 12500
    dim3 ggrid((N_NODES + 31) / 32);             // 1563

    // ---- build CSR: decoupled counting sort, zero global atomics ----
    binhist<<<NB1, blk, 0, stream>>>(dst, cnt);
    binscan<<<1, 128, 0, stream>>>(cnt, off, bstart);
    binscatter<<<NB1, blk, 0, stream>>>(src, dst, ew, off, slab);
    sort_bucket<<<NBKT, 512, 0, stream>>>(slab, bstart, edges, start);

    // ---- layer 1: hw = x@w1 (overwrites slab); h = relu(agg+b1) -> d_out ----
    gemm_tile<N_FEAT><<<ggrid, blk, 0, stream>>>(x, w1, hw);
    gcn_agg<true><<<ngrid, blk, 0, stream>>>(hw, edges, start, b1, out);

    // ---- layer 2: hw = h@w2; out = agg + b2 ----
    gemm_tile<N_HID><<<ggrid, blk, 0, stream>>>(out, w2, hw);
    gcn_agg<false><<<ngrid, blk, 0, stream>>>(hw, edges, start, b2, out);
}

// Round 6
// 144.541 us; speedup vs baseline: 2.2527x; 1.0842x over previous
//
#include <hip/hip_runtime.h>

#define N_NODES 50000
#define N_EDGES 800000
#define N_FEAT  128
#define N_HID   64

#define BKT_LOG 9
#define BKT_SZ  512                                  // nodes per bucket
#define NBKT    ((N_NODES + BKT_SZ - 1) / BKT_SZ)    // 98
#define CH      4096                                 // edges per partition block
#define NB1     ((N_EDGES + CH - 1) / CH)            // 196

__device__ inline void fma4(float4& acc, float s, const float4& w) {
    acc.x = fmaf(s, w.x, acc.x);
    acc.y = fmaf(s, w.y, acc.y);
    acc.z = fmaf(s, w.z, acc.z);
    acc.w = fmaf(s, w.w, acc.w);
}

// ---------- tiled GEMM: o[row][col] = sum_k a[row*K+k] * w[k*64+col] ----------
template <int K>
__global__ __launch_bounds__(256) void gemm_tile(const float* __restrict__ a,
                                                 const float* __restrict__ w,
                                                 float* __restrict__ o) {
    __shared__ float lw[K * N_HID];
    int tid = threadIdx.x;
    for (int idx = tid * 4; idx < K * N_HID; idx += 256 * 4)
        *(float4*)&lw[idx] = *(const float4*)&w[idx];
    __syncthreads();

    int row0 = blockIdx.x * 32 + (tid >> 4) * 2;
    if (row0 >= N_NODES) return;
    bool two = (row0 + 1) < N_NODES;
    int c4 = (tid & 15) * 4;

    const float* a0 = a + (long)row0 * K;
    const float* a1 = two ? (a0 + K) : a0;

    float4 acc0 = make_float4(0.f, 0.f, 0.f, 0.f);
    float4 acc1 = acc0;

#pragma unroll 8
    for (int k4 = 0; k4 < K / 4; ++k4) {
        float4 xa = *(const float4*)(a0 + k4 * 4);
        float4 xb = *(const float4*)(a1 + k4 * 4);
        const float* wk = &lw[(k4 * 4) * N_HID + c4];
        float4 w0 = *(const float4*)(wk);
        float4 w1 = *(const float4*)(wk + N_HID);
        float4 w2 = *(const float4*)(wk + 2 * N_HID);
        float4 w3 = *(const float4*)(wk + 3 * N_HID);
        fma4(acc0, xa.x, w0); fma4(acc1, xb.x, w0);
        fma4(acc0, xa.y, w1); fma4(acc1, xb.y, w1);
        fma4(acc0, xa.z, w2); fma4(acc1, xb.z, w2);
        fma4(acc0, xa.w, w3); fma4(acc1, xb.w, w3);
    }

    float* op = o + (long)row0 * N_HID + c4;
    *(float4*)op = acc0;
    if (two) *(float4*)(op + N_HID) = acc1;
}

// ---------- CSR build: decoupled radix partition (NO global atomics) ----------
__global__ __launch_bounds__(256) void binhist(const int* __restrict__ dst,
                                               int* __restrict__ cnt) {
    __shared__ int h[NBKT];
    int t = threadIdx.x;
    if (t < NBKT) h[t] = 0;
    __syncthreads();
    int e0 = blockIdx.x * CH;
    for (int i = t; i < CH; i += 256) {
        int e = e0 + i;
        if (e < N_EDGES) atomicAdd(&h[dst[e] >> BKT_LOG], 1);
    }
    __syncthreads();
    if (t < NBKT) cnt[blockIdx.x * NBKT + t] = h[t];
}

__global__ __launch_bounds__(128) void binscan(const int* __restrict__ cnt,
                                               int* __restrict__ off,
                                               int* __restrict__ bstart) {
    __shared__ int tot[NBKT];
    int t = threadIdx.x;
    if (t < NBKT) {
        int s = 0;
        for (int b = 0; b < NB1; ++b) s += cnt[b * NBKT + t];
        tot[t] = s;
    }
    __syncthreads();
    if (t == 0) {
        int s = 0;
        for (int i = 0; i < NBKT; ++i) { bstart[i] = s; s += tot[i]; }
        bstart[NBKT] = s;
    }
    __syncthreads();
    if (t < NBKT) {
        int run = bstart[t];
        for (int b = 0; b < NB1; ++b) {
            off[b * NBKT + t] = run;
            run += cnt[b * NBKT + t];
        }
    }
}

__global__ __launch_bounds__(256) void binscatter(const int* __restrict__ src,
                                                  const int* __restrict__ dst,
                                                  const float* __restrict__ ew,
                                                  const int* __restrict__ off,
                                                  uint2* __restrict__ slab) {
    __shared__ int cur[NBKT];
    int t = threadIdx.x;
    if (t < NBKT) cur[t] = off[blockIdx.x * NBKT + t];
    __syncthreads();
    int e0 = blockIdx.x * CH;
    for (int i = t; i < CH; i += 256) {
        int e = e0 + i;
        if (e >= N_EDGES) continue;
        int d = dst[e];
        int bin = d >> BKT_LOG;
        int p = atomicAdd(&cur[bin], 1);
        slab[p] = make_uint2((unsigned)src[e] | ((unsigned)(d & (BKT_SZ - 1)) << 16),
                             __float_as_uint(ew[e]));
    }
}

__global__ __launch_bounds__(512) void sort_bucket(const uint2* __restrict__ slab,
                                                   const int* __restrict__ bstart,
                                                   int2* __restrict__ edges,
                                                   int* __restrict__ start) {
    __shared__ int h[BKT_SZ];
    __shared__ int sc[BKT_SZ];
    int b = blockIdx.x;
    int t = threadIdx.x;
    int base = bstart[b];
    int c = bstart[b + 1] - base;

    h[t] = 0;
    __syncthreads();
    for (int i = t; i < c; i += 512)
        atomicAdd(&h[(slab[base + i].x >> 16) & (BKT_SZ - 1)], 1);
    __syncthreads();
    int v = h[t];
    sc[t] = v;
    __syncthreads();
    for (int o = 1; o < BKT_SZ; o <<= 1) {
        int u = (t >= o) ? sc[t - o] : 0;
        __syncthreads();
        sc[t] += u;
        __syncthreads();
    }
    int excl = sc[t] - v;
    int g = (b << BKT_LOG) + t;
    if (g < N_NODES) start[g] = base + excl;
    if (b == NBKT - 1 && t == 0) start[N_NODES] = N_EDGES;
    h[t] = base + excl;
    __syncthreads();
    for (int i = t; i < c; i += 512) {
        uint2 r = slab[base + i];
        int p = atomicAdd(&h[(r.x >> 16) & (BKT_SZ - 1)], 1);
        edges[p] = make_int2((int)(r.x & 0xFFFF), (int)r.y);
    }
}

// ---------- pull aggregation v2: 4 edges x float4 features per wave-step ----------
// lane = es*16 + f4g : es = edge slot (0..3), f4g = feature group (0..15)
// 8 edges in flight per loop trip (2 gathers/lane), xor-reduce over es at end.
template <bool RELU>
__global__ __launch_bounds__(256) void gcn_agg(const float* __restrict__ hw,
                                               const int2* __restrict__ edges,
                                               const int* __restrict__ start,
                                               const float* __restrict__ b,
                                               float* __restrict__ o) {
    int n = (blockIdx.x * blockDim.x + threadIdx.x) >> 6;   // node (one wave)
    if (n >= N_NODES) return;
    int lane = threadIdx.x & 63;
    int es = lane >> 4;            // 0..3
    int f4 = (lane & 15) * 4;      // 0,4,...,60

    int i0 = start[n], i1 = start[n + 1];
    float4 acc = make_float4(0.f, 0.f, 0.f, 0.f);

    for (int base = i0; base < i1; base += 8) {
        int ia = base + es;
        int ib = base + 4 + es;
        int ca = min(ia, i1 - 1);
        int cb = min(ib, i1 - 1);
        int2 eda = edges[ca];
        int2 edb = edges[cb];
        float wa = (ia < i1) ? __int_as_float(eda.y) : 0.f;
        float wb = (ib < i1) ? __int_as_float(edb.y) : 0.f;
        float4 va = *(const float4*)&hw[(long)eda.x * N_HID + f4];
        float4 vb = *(const float4*)&hw[(long)edb.x * N_HID + f4];
        fma4(acc, wa, va);
        fma4(acc, wb, vb);
    }

    // reduce across the 4 edge slots (lanes differing in bits 4,5)
    acc.x += __shfl_xor(acc.x, 16); acc.y += __shfl_xor(acc.y, 16);
    acc.z += __shfl_xor(acc.z, 16); acc.w += __shfl_xor(acc.w, 16);
    acc.x += __shfl_xor(acc.x, 32); acc.y += __shfl_xor(acc.y, 32);
    acc.z += __shfl_xor(acc.z, 32); acc.w += __shfl_xor(acc.w, 32);

    if (es == 0) {
        float4 bias = *(const float4*)&b[f4];
        acc.x += bias.x; acc.y += bias.y; acc.z += bias.z; acc.w += bias.w;
        if (RELU) {
            acc.x = fmaxf(acc.x, 0.f); acc.y = fmaxf(acc.y, 0.f);
            acc.z = fmaxf(acc.z, 0.f); acc.w = fmaxf(acc.w, 0.f);
        }
        *(float4*)&o[(long)n * N_HID + f4] = acc;
    }
}

extern "C" void kernel_launch(void* const* d_in, const int* in_sizes, int n_in,
                              void* d_out, int out_size, void* d_ws, size_t ws_size,
                              hipStream_t stream) {
    const float* x  = (const float*)d_in[0];
    const int*   ei = (const int*)d_in[1];   // [2, E] flat: src then dst
    const float* ew = (const float*)d_in[2];
    const float* w1 = (const float*)d_in[3];
    const float* b1 = (const float*)d_in[4];
    const float* w2 = (const float*)d_in[5];
    const float* b2 = (const float*)d_in[6];
    float* out = (float*)d_out;

    const int* src = ei;
    const int* dst = ei + N_EDGES;

    char* ws = (char*)d_ws;
    const size_t SLAB_B = (size_t)N_EDGES * sizeof(uint2);            // 6.4 MB
    const size_t REGA   = (size_t)N_NODES * N_HID * sizeof(float);    // 12.8 MB
    float* hw    = (float*)ws;
    uint2* slab  = (uint2*)ws;
    int*   cnt   = (int*)(ws + SLAB_B);
    int*   off   = cnt + NB1 * NBKT;
    int2*  edges = (int2*)(ws + REGA);
    int*   start = (int*)(ws + REGA + SLAB_B);
    int*   bstart = start + N_NODES + 3;

    dim3 blk(256);
    dim3 ngrid((N_NODES * N_HID + 255) / 256);   // 12500 (4 nodes / block)
    dim3 ggrid((N_NODES + 31) / 32);             // 1563

    // ---- build CSR: decoupled counting sort, zero global atomics ----
    binhist<<<NB1, blk, 0, stream>>>(dst, cnt);
    binscan<<<1, 128, 0, stream>>>(cnt, off, bstart);
    binscatter<<<NB1, blk, 0, stream>>>(src, dst, ew, off, slab);
    sort_bucket<<<NBKT, 512, 0, stream>>>(slab, bstart, edges, start);

    // ---- layer 1: hw = x@w1 (overwrites slab); h = relu(agg+b1) -> d_out ----
    gemm_tile<N_FEAT><<<ggrid, blk, 0, stream>>>(x, w1, hw);
    gcn_agg<true><<<ngrid, blk, 0, stream>>>(hw, edges, start, b1, out);

    // ---- layer 2: hw = h@w2; out = agg + b2 ----
    gemm_tile<N_HID><<<ggrid, blk, 0, stream>>>(out, w2, hw);
    gcn_agg<false><<<ngrid, blk, 0, stream>>>(hw, edges, start, b2, out);
}

// Round 7
// 142.838 us; speedup vs baseline: 2.2796x; 1.0119x over previous
//
#include <hip/hip_runtime.h>

#define N_NODES 50000
#define N_EDGES 800000
#define N_FEAT  128
#define N_HID   64

#define BKT_LOG 9
#define BKT_SZ  512                                  // nodes per bucket
#define NBKT    ((N_NODES + BKT_SZ - 1) / BKT_SZ)    // 98
#define CH      4096                                 // edges per partition block
#define NB1     ((N_EDGES + CH - 1) / CH)            // 196

__device__ inline void fma4(float4& acc, float s, const float4& w) {
    acc.x = fmaf(s, w.x, acc.x);
    acc.y = fmaf(s, w.y, acc.y);
    acc.z = fmaf(s, w.z, acc.z);
    acc.w = fmaf(s, w.w, acc.w);
}

// ---------- tiled GEMM: o[row][col] = sum_k a[row*K+k] * w[k*64+col] ----------
template <int K>
__global__ __launch_bounds__(256) void gemm_tile(const float* __restrict__ a,
                                                 const float* __restrict__ w,
                                                 float* __restrict__ o) {
    __shared__ float lw[K * N_HID];
    int tid = threadIdx.x;
    for (int idx = tid * 4; idx < K * N_HID; idx += 256 * 4)
        *(float4*)&lw[idx] = *(const float4*)&w[idx];
    __syncthreads();

    int row0 = blockIdx.x * 32 + (tid >> 4) * 2;
    if (row0 >= N_NODES) return;
    bool two = (row0 + 1) < N_NODES;
    int c4 = (tid & 15) * 4;

    const float* a0 = a + (long)row0 * K;
    const float* a1 = two ? (a0 + K) : a0;

    float4 acc0 = make_float4(0.f, 0.f, 0.f, 0.f);
    float4 acc1 = acc0;

#pragma unroll 8
    for (int k4 = 0; k4 < K / 4; ++k4) {
        float4 xa = *(const float4*)(a0 + k4 * 4);
        float4 xb = *(const float4*)(a1 + k4 * 4);
        const float* wk = &lw[(k4 * 4) * N_HID + c4];
        float4 w0 = *(const float4*)(wk);
        float4 w1 = *(const float4*)(wk + N_HID);
        float4 w2 = *(const float4*)(wk + 2 * N_HID);
        float4 w3 = *(const float4*)(wk + 3 * N_HID);
        fma4(acc0, xa.x, w0); fma4(acc1, xb.x, w0);
        fma4(acc0, xa.y, w1); fma4(acc1, xb.y, w1);
        fma4(acc0, xa.z, w2); fma4(acc1, xb.z, w2);
        fma4(acc0, xa.w, w3); fma4(acc1, xb.w, w3);
    }

    float* op = o + (long)row0 * N_HID + c4;
    *(float4*)op = acc0;
    if (two) *(float4*)(op + N_HID) = acc1;
}

// ---------- CSR build: decoupled radix partition (NO global atomics) ----------
// phase 1: per-block LDS histogram; writes block-major AND bucket-major copies
__global__ __launch_bounds__(256) void binhist(const int* __restrict__ dst,
                                               int* __restrict__ cnt,
                                               int* __restrict__ cnt_t) {
    __shared__ int h[NBKT];
    int t = threadIdx.x;
    if (t < NBKT) h[t] = 0;
    __syncthreads();
    int e0 = blockIdx.x * CH;
    for (int i = t; i < CH; i += 256) {
        int e = e0 + i;
        if (e < N_EDGES) atomicAdd(&h[dst[e] >> BKT_LOG], 1);
    }
    __syncthreads();
    if (t < NBKT) {
        int v = h[t];
        cnt[blockIdx.x * NBKT + t] = v;
        cnt_t[t * NB1 + blockIdx.x] = v;
    }
}

// phase 2: bucket totals from contiguous rows (int4), LDS scan, emit offsets
__global__ __launch_bounds__(128) void binscan(const int* __restrict__ cnt_t,
                                               int* __restrict__ off,
                                               int* __restrict__ bstart) {
    __shared__ int tot[128];
    int t = threadIdx.x;
    int s = 0;
    if (t < NBKT) {
        const int4* p = (const int4*)(cnt_t + t * NB1);   // NB1 % 4 == 0
#pragma unroll 7
        for (int q = 0; q < NB1 / 4; ++q) {
            int4 v = p[q];
            s += v.x + v.y + v.z + v.w;
        }
    }
    tot[t] = s;
    __syncthreads();
    for (int o = 1; o < 128; o <<= 1) {
        int u = (t >= o) ? tot[t - o] : 0;
        __syncthreads();
        tot[t] += u;
        __syncthreads();
    }
    int excl = tot[t] - s;
    if (t < NBKT) {
        bstart[t] = excl;
        int run = excl;
        const int* p = cnt_t + t * NB1;
        for (int bdx = 0; bdx < NB1; ++bdx) {
            off[bdx * NBKT + t] = run;
            run += p[bdx];
        }
        if (t == NBKT - 1) bstart[NBKT] = run;   // == N_EDGES
    }
}

// phase 3: place edges into bucket-partitioned slab via LDS cursors
__global__ __launch_bounds__(256) void binscatter(const int* __restrict__ src,
                                                  const int* __restrict__ dst,
                                                  const float* __restrict__ ew,
                                                  const int* __restrict__ off,
                                                  uint2* __restrict__ slab) {
    __shared__ int cur[NBKT];
    int t = threadIdx.x;
    if (t < NBKT) cur[t] = off[blockIdx.x * NBKT + t];
    __syncthreads();
    int e0 = blockIdx.x * CH;
    for (int i = t; i < CH; i += 256) {
        int e = e0 + i;
        if (e >= N_EDGES) continue;
        int d = dst[e];
        int bin = d >> BKT_LOG;
        int p = atomicAdd(&cur[bin], 1);
        slab[p] = make_uint2((unsigned)src[e] | ((unsigned)(d & (BKT_SZ - 1)) << 16),
                             __float_as_uint(ew[e]));
    }
}

// phase 4: per-bucket LDS counting sort -> final edges + start[]
__global__ __launch_bounds__(512) void sort_bucket(const uint2* __restrict__ slab,
                                                   const int* __restrict__ bstart,
                                                   int2* __restrict__ edges,
                                                   int* __restrict__ start) {
    __shared__ int h[BKT_SZ];
    __shared__ int sc[BKT_SZ];
    int b = blockIdx.x;
    int t = threadIdx.x;
    int base = bstart[b];
    int c = bstart[b + 1] - base;

    h[t] = 0;
    __syncthreads();
    for (int i = t; i < c; i += 512)
        atomicAdd(&h[(slab[base + i].x >> 16) & (BKT_SZ - 1)], 1);
    __syncthreads();
    int v = h[t];
    sc[t] = v;
    __syncthreads();
    for (int o = 1; o < BKT_SZ; o <<= 1) {
        int u = (t >= o) ? sc[t - o] : 0;
        __syncthreads();
        sc[t] += u;
        __syncthreads();
    }
    int excl = sc[t] - v;
    int g = (b << BKT_LOG) + t;
    if (g < N_NODES) start[g] = base + excl;
    if (b == NBKT - 1 && t == 0) start[N_NODES] = N_EDGES;
    h[t] = base + excl;
    __syncthreads();
    for (int i = t; i < c; i += 512) {
        uint2 r = slab[base + i];
        int p = atomicAdd(&h[(r.x >> 16) & (BKT_SZ - 1)], 1);
        edges[p] = make_int2((int)(r.x & 0xFFFF), (int)r.y);
    }
}

// ---------- pull aggregation v3: 16 edge slots / trip, predicated (no waste) ----------
// lane = es*16 + f4g; per trip each lane issues up to 4 independent gathers.
template <bool RELU>
__global__ __launch_bounds__(256) void gcn_agg(const float* __restrict__ hw,
                                               const int2* __restrict__ edges,
                                               const int* __restrict__ start,
                                               const float* __restrict__ b,
                                               float* __restrict__ o) {
    int n = (blockIdx.x * blockDim.x + threadIdx.x) >> 6;
    if (n >= N_NODES) return;
    int lane = threadIdx.x & 63;
    int es = lane >> 4;            // 0..3
    int f4 = (lane & 15) * 4;      // 0,4,...,60

    int i0 = start[n], i1 = start[n + 1];
    float4 acc = make_float4(0.f, 0.f, 0.f, 0.f);

    for (int base = i0; base < i1; base += 16) {
        int ia = base + es;
        int ib = base + 4 + es;
        int ic = base + 8 + es;
        int id = base + 12 + es;
        float wa = 0.f, wb = 0.f, wc = 0.f, wd = 0.f;
        float4 va = make_float4(0.f, 0.f, 0.f, 0.f);
        float4 vb = va, vc = va, vd = va;
        if (ia < i1) {                       // uniform per 16-lane group
            int2 e = edges[ia];
            wa = __int_as_float(e.y);
            va = *(const float4*)&hw[(long)e.x * N_HID + f4];
        }
        if (ib < i1) {
            int2 e = edges[ib];
            wb = __int_as_float(e.y);
            vb = *(const float4*)&hw[(long)e.x * N_HID + f4];
        }
        if (ic < i1) {
            int2 e = edges[ic];
            wc = __int_as_float(e.y);
            vc = *(const float4*)&hw[(long)e.x * N_HID + f4];
        }
        if (id < i1) {
            int2 e = edges[id];
            wd = __int_as_float(e.y);
            vd = *(const float4*)&hw[(long)e.x * N_HID + f4];
        }
        fma4(acc, wa, va);
        fma4(acc, wb, vb);
        fma4(acc, wc, vc);
        fma4(acc, wd, vd);
    }

    // reduce across the 4 edge slots (lanes differing in bits 4,5)
    acc.x += __shfl_xor(acc.x, 16); acc.y += __shfl_xor(acc.y, 16);
    acc.z += __shfl_xor(acc.z, 16); acc.w += __shfl_xor(acc.w, 16);
    acc.x += __shfl_xor(acc.x, 32); acc.y += __shfl_xor(acc.y, 32);
    acc.z += __shfl_xor(acc.z, 32); acc.w += __shfl_xor(acc.w, 32);

    if (es == 0) {
        float4 bias = *(const float4*)&b[f4];
        acc.x += bias.x; acc.y += bias.y; acc.z += bias.z; acc.w += bias.w;
        if (RELU) {
            acc.x = fmaxf(acc.x, 0.f); acc.y = fmaxf(acc.y, 0.f);
            acc.z = fmaxf(acc.z, 0.f); acc.w = fmaxf(acc.w, 0.f);
        }
        *(float4*)&o[(long)n * N_HID + f4] = acc;
    }
}

extern "C" void kernel_launch(void* const* d_in, const int* in_sizes, int n_in,
                              void* d_out, int out_size, void* d_ws, size_t ws_size,
                              hipStream_t stream) {
    const float* x  = (const float*)d_in[0];
    const int*   ei = (const int*)d_in[1];   // [2, E] flat: src then dst
    const float* ew = (const float*)d_in[2];
    const float* w1 = (const float*)d_in[3];
    const float* b1 = (const float*)d_in[4];
    const float* w2 = (const float*)d_in[5];
    const float* b2 = (const float*)d_in[6];
    float* out = (float*)d_out;

    const int* src = ei;
    const int* dst = ei + N_EDGES;

    // disjoint workspace (ws is 256 MB; ~26 MB used)
    char* ws = (char*)d_ws;
    float* hw     = (float*)ws;                                   // 12.8 MB
    uint2* slab   = (uint2*)(ws + (size_t)13 * 1024 * 1024);      // 6.4 MB
    int2*  edges  = (int2*)(ws + (size_t)20 * 1024 * 1024);       // 6.4 MB
    int*   start  = (int*)(ws + (size_t)27 * 1024 * 1024);        // 50001 ints
    int*   bstart = start + N_NODES + 3;                          // 99 ints
    int*   cnt    = bstart + NBKT + 3;                            // NB1*NBKT
    int*   cnt_t  = cnt + NB1 * NBKT;                             // NBKT*NB1
    int*   off    = cnt_t + NBKT * NB1;                           // NB1*NBKT

    dim3 blk(256);
    dim3 ngrid((N_NODES * N_HID + 255) / 256);   // 12500 (4 nodes / block)
    dim3 ggrid((N_NODES + 31) / 32);             // 1563

    // ---- build CSR: decoupled counting sort, zero global atomics ----
    binhist<<<NB1, blk, 0, stream>>>(dst, cnt, cnt_t);
    binscan<<<1, 128, 0, stream>>>(cnt_t, off, bstart);
    binscatter<<<NB1, blk, 0, stream>>>(src, dst, ew, off, slab);
    sort_bucket<<<NBKT, 512, 0, stream>>>(slab, bstart, edges, start);

    // ---- layer 1: hw = x@w1; h = relu(agg+b1) -> d_out ----
    gemm_tile<N_FEAT><<<ggrid, blk, 0, stream>>>(x, w1, hw);
    gcn_agg<true><<<ngrid, blk, 0, stream>>>(hw, edges, start, b1, out);

    // ---- layer 2: hw = h@w2; out = agg + b2 ----
    gemm_tile<N_HID><<<ggrid, blk, 0, stream>>>(out, w2, hw);
    gcn_agg<false><<<ngrid, blk, 0, stream>>>(hw, edges, start, b2, out);
}